// Round 1
// 465.951 us; speedup vs baseline: 1.0383x; 1.0383x over previous
//
#include <hip/hip_runtime.h>

#define B_   32
#define N_   512
#define G_   64
#define T_   16
#define D_   256
#define E_   500000
#define M_   1024
#define S_   (B_ * N_)          // 16384 distinct source rows
#define TT_  2048               // B_*G_ distinct target rows
#define TD_  (T_ * D_)          // 4096 floats between scope_type rows
#define NEG_ (-10000000000.0f)

// ws layout (bytes) — P is gone: lemma preds computed per-edge directly.
#define WS_WT    0              // 256 KiB  (W transposed, fp32)
#define WS_WGB   262144         // 1 MiB    (Wg bf16, 2048x256)
#define WS_SCB   2097152        // 8 MiB    (scope_type bf16, 16384x256)
#define WS_FLAG  10485760       // 4 B

typedef short  short8 __attribute__((ext_vector_type(8)));

__device__ __forceinline__ unsigned short f2bf(float x) {
  union { float f; unsigned int u; } v; v.f = x;
  const unsigned int r = (v.u + 0x7fffu + ((v.u >> 16) & 1u)) >> 16;
  return (unsigned short)r;
}

__device__ __forceinline__ float bf2f(unsigned short u) {
  union { unsigned int u; float f; } v;
  v.u = ((unsigned int)u) << 16;
  return v.f;
}

// ---------------------------------------------------------------------------
// kernel 0: classify tree_mask storage. flag = 1 (bool), 2 (f32), 0 (i32).
// ---------------------------------------------------------------------------
__global__ __launch_bounds__(256) void detect_mask_dtype(
    const unsigned char* __restrict__ tm, int* __restrict__ flag) {
  __shared__ int sA, sB;
  if (threadIdx.x == 0) { sA = 0; sB = 0; }
  __syncthreads();
  int a = 0, b3 = 0;
  for (int i = threadIdx.x; i < B_ * N_; i += 256) {
    const int r = i & 3;
    const unsigned char v = tm[i];
    if (r == 1) a |= v;
    else if (r == 3) b3 |= v;
  }
  if (a)  atomicOr(&sA, 1);
  if (b3) atomicOr(&sB, 1);
  __syncthreads();
  if (threadIdx.x == 0) flag[0] = sA ? 1 : (sB ? 2 : 0);
}

// ---------------------------------------------------------------------------
// kernel 1a: Wt[f][d] = W[d][f]  (32x32 LDS tiles, +1 pad)
// ---------------------------------------------------------------------------
__global__ __launch_bounds__(256) void transpose_w(
    const float* __restrict__ W, float* __restrict__ Wt) {
  __shared__ float tile[32][33];
  const int bi = blockIdx.x >> 3;
  const int bj = blockIdx.x & 7;
  const int tx = threadIdx.x & 31;
  const int ty = threadIdx.x >> 5;
#pragma unroll
  for (int r = 0; r < 4; r++)
    tile[ty + r * 8][tx] = W[(size_t)(bi * 32 + ty + r * 8) * D_ + bj * 32 + tx];
  __syncthreads();
#pragma unroll
  for (int r = 0; r < 4; r++)
    Wt[(size_t)(bj * 32 + ty + r * 8) * D_ + bi * 32 + tx] =
        tile[tx][ty + r * 8];
}

// ---------------------------------------------------------------------------
// kernel 1b: Wg_bf16[j][d] = bf16( sum_f goal_type[j][f] * Wt[f][d] )
// fp32 math, bf16 store (feeds the per-edge dot).
// ---------------------------------------------------------------------------
__global__ __launch_bounds__(256) void wg_gemm(
    const float* __restrict__ goal, const float* __restrict__ Wt,
    unsigned short* __restrict__ Wgb) {
  __shared__ float g[8][256];
  const int j0 = blockIdx.x * 8;
  const int d  = threadIdx.x;
  {
    const int lane = threadIdx.x & 63;
    const int r0   = threadIdx.x >> 6;
#pragma unroll
    for (int rr = 0; rr < 2; rr++) {
      const int row = rr * 4 + r0;
      const float4 v = *reinterpret_cast<const float4*>(
          goal + (size_t)(j0 + row) * TD_ + lane * 4);
      float* dst = &g[row][lane * 4];
      dst[0] = v.x; dst[1] = v.y; dst[2] = v.z; dst[3] = v.w;
    }
  }
  __syncthreads();
  float acc[8];
#pragma unroll
  for (int jj = 0; jj < 8; jj++) acc[jj] = 0.f;
#pragma unroll 4
  for (int f = 0; f < D_; f++) {
    const float w = Wt[(size_t)f * D_ + d];
#pragma unroll
    for (int jj = 0; jj < 8; jj++) acc[jj] = fmaf(g[jj][f], w, acc[jj]);
  }
#pragma unroll
  for (int jj = 0; jj < 8; jj++)
    Wgb[(size_t)(j0 + jj) * D_ + d] = f2bf(acc[jj]);
}

// ---------------------------------------------------------------------------
// kernel 1c: Sc_bf16[s][d] = bf16(scope_token_reprs[s][0][d]), s in [0,16384)
// ---------------------------------------------------------------------------
__global__ __launch_bounds__(256) void cast_scope(
    const float* __restrict__ scope, unsigned short* __restrict__ scb) {
  const int q   = blockIdx.x * 256 + threadIdx.x;  // quad id, < 16384*64
  const int row = q >> 6;
  const int c4  = q & 63;
  const float4 v =
      *reinterpret_cast<const float4*>(scope + (size_t)row * TD_ + c4 * 4);
  ushort4 o;
  o.x = f2bf(v.x); o.y = f2bf(v.y); o.z = f2bf(v.z); o.w = f2bf(v.w);
  *reinterpret_cast<ushort4*>(&scb[(size_t)row * D_ + c4 * 4]) = o;
}

// ---------------------------------------------------------------------------
// kernel 2: per-edge dot — lemma_preds[e] = Sc[src_e] . Wg[tgt_e] + bias.
// 16 lanes per edge, 16 bf16 elems/lane (2x b128), shfl_xor tree reduce.
// Replaces the dense 16384x2048 P GEMM (only 1.5% of P was consumed) and
// the 134 MB HBM round-trip it implied.
// ---------------------------------------------------------------------------
__global__ __launch_bounds__(256) void edge_dot(
    const unsigned short* __restrict__ scb,
    const unsigned short* __restrict__ wgb,
    const int* __restrict__ edges, const float* __restrict__ bias,
    float* __restrict__ out) {
  const int tid = threadIdx.x;
  const int grp = tid >> 4;                 // 16 edges per block
  const int l   = tid & 15;
  const int e   = blockIdx.x * 16 + grp;    // grid sized exactly: no guard
  const int s = edges[e];
  const int t = edges[E_ + e];
  // lane l covers elems [l*8, l*8+8) and [128+l*8, 128+l*8+8):
  // both halves are 256 B-contiguous across the 16-lane group.
  const short8 a0 = *reinterpret_cast<const short8*>(&scb[(size_t)s * D_ + l * 8]);
  const short8 a1 = *reinterpret_cast<const short8*>(&scb[(size_t)s * D_ + 128 + l * 8]);
  const short8 b0 = *reinterpret_cast<const short8*>(&wgb[(size_t)t * D_ + l * 8]);
  const short8 b1 = *reinterpret_cast<const short8*>(&wgb[(size_t)t * D_ + 128 + l * 8]);
  float acc = 0.f;
#pragma unroll
  for (int i = 0; i < 8; i++) {
    acc = fmaf(bf2f((unsigned short)a0[i]), bf2f((unsigned short)b0[i]), acc);
    acc = fmaf(bf2f((unsigned short)a1[i]), bf2f((unsigned short)b1[i]), acc);
  }
  acc += __shfl_xor(acc, 1);
  acc += __shfl_xor(acc, 2);
  acc += __shfl_xor(acc, 4);
  acc += __shfl_xor(acc, 8);
  if (l == 0) out[e] = acc + bias[0];
}

// ---------------------------------------------------------------------------
// kernel 4: lm_preds (unchanged — verified)
// ---------------------------------------------------------------------------
__global__ __launch_bounds__(256) void lm_kernel(
    const float* __restrict__ scope, const int* __restrict__ lm_idx,
    const int* __restrict__ batch_pts, const void* __restrict__ tree_mask,
    const int* __restrict__ flag_p, float* __restrict__ out) {
  __shared__ float cand[32][260];
  __shared__ unsigned char tmask[32];
  __shared__ int mlist[M_];
  __shared__ int mcnt;
  const int b  = blockIdx.x >> 4;
  const int n0 = (blockIdx.x & 15) * 32;
  const int t  = threadIdx.x;

  if (t == 0) mcnt = 0;
  {
    const int lane = t & 63;
    const int r0   = t >> 6;
#pragma unroll
    for (int rr = 0; rr < 8; rr++) {
      const int row = rr * 4 + r0;
      const float4 v = *reinterpret_cast<const float4*>(
          scope + (size_t)(b * N_ + n0 + row) * TD_ + lane * 4);
      float* dst = &cand[row][lane * 4];
      dst[0] = v.x; dst[1] = v.y; dst[2] = v.z; dst[3] = v.w;
    }
  }
  const int flag = flag_p[0];
  if (t < 32) {
    const int n = b * N_ + n0 + t;
    int v;
    if (flag == 1)      v = ((const unsigned char*)tree_mask)[n] != 0;
    else if (flag == 2) v = ((const float*)tree_mask)[n] != 0.0f;
    else                v = ((const int*)tree_mask)[n] != 0;
    tmask[t] = (unsigned char)v;
  }
  __syncthreads();

#pragma unroll
  for (int c = 0; c < M_ / 256; c++) {
    const int m = c * 256 + t;
    if (batch_pts[m] == b) {
      const int p = atomicAdd(&mcnt, 1);
      mlist[p] = m;
    }
  }
  __syncthreads();
  const int cnt = mcnt;

  const int nl = t >> 3;
  const int kg = t & 7;
  for (int k = 0; k < cnt; k++) {
    const int m = mlist[k];
    const float4* q =
        reinterpret_cast<const float4*>(scope + (size_t)lm_idx[m] * D_);
    float acc = 0.f;
#pragma unroll
    for (int i = 0; i < 8; i++) {
      const int f4 = kg * 8 + i;
      const float4 qv = q[f4];
      const float* cp = &cand[nl][f4 * 4];
      acc += qv.x * cp[0] + qv.y * cp[1] + qv.z * cp[2] + qv.w * cp[3];
    }
    acc += __shfl_xor(acc, 1);
    acc += __shfl_xor(acc, 2);
    acc += __shfl_xor(acc, 4);
    if (kg == 0)
      out[(size_t)m * N_ + (n0 + nl)] = tmask[nl] ? acc : NEG_;
  }
}

// ---------------------------------------------------------------------------
extern "C" void kernel_launch(void* const* d_in, const int* in_sizes, int n_in,
                              void* d_out, int out_size, void* d_ws,
                              size_t ws_size, hipStream_t stream) {
  const float* scope = (const float*)d_in[0];
  const float* goal  = (const float*)d_in[1];
  const float* W     = (const float*)d_in[2];
  const float* bias  = (const float*)d_in[3];
  const int*   edges = (const int*)d_in[4];
  const int*   lmidx = (const int*)d_in[5];
  const int*   bpts  = (const int*)d_in[6];
  const void*  tmask = d_in[7];

  float* out = (float*)d_out;
  char*  ws  = (char*)d_ws;
  float*          Wt   = (float*)(ws + WS_WT);
  unsigned short* Wgb  = (unsigned short*)(ws + WS_WGB);
  unsigned short* scb  = (unsigned short*)(ws + WS_SCB);
  int*            flag = (int*)(ws + WS_FLAG);

  detect_mask_dtype<<<1, 256, 0, stream>>>((const unsigned char*)tmask, flag);
  transpose_w<<<64, 256, 0, stream>>>(W, Wt);
  wg_gemm<<<TT_ / 8, 256, 0, stream>>>(goal, Wt, Wgb);
  cast_scope<<<(S_ * 64) / 256, 256, 0, stream>>>(scope, scb);
  edge_dot<<<E_ / 16, 256, 0, stream>>>(scb, Wgb, edges, bias, out);
  lm_kernel<<<B_ * 16, 256, 0, stream>>>(scope, lmidx, bpts, tmask, flag,
                                         out + E_);
}

// Round 5
// 437.627 us; speedup vs baseline: 1.1055x; 1.0647x over previous
//
#include <hip/hip_runtime.h>

#define B_   32
#define N_   512
#define G_   64
#define T_   16
#define D_   256
#define E_   500000
#define M_   1024
#define S_   (B_ * N_)          // 16384 distinct source rows
#define TT_  2048               // B_*G_ distinct target rows
#define TD_  (T_ * D_)          // 4096 floats between scope_type rows
#define NEG_ (-10000000000.0f)

// ws layout (bytes)
#define WS_WT    0              // 256 KiB  (W transposed, fp32)
#define WS_WGB   262144         // 1 MiB    (Wg bf16, 2048x256)
#define WS_SCB   2097152        // 8 MiB    (scope_type bf16, 16384x256)

typedef short  short8 __attribute__((ext_vector_type(8)));

__device__ __forceinline__ unsigned short f2bf(float x) {
  union { float f; unsigned int u; } v; v.f = x;
  const unsigned int r = (v.u + 0x7fffu + ((v.u >> 16) & 1u)) >> 16;
  return (unsigned short)r;
}

__device__ __forceinline__ float bf2f(unsigned short u) {
  union { unsigned int u; float f; } v;
  v.u = ((unsigned int)u) << 16;
  return v.f;
}

// ---------------------------------------------------------------------------
// K1: fused  lm_kernel (512 blocks, inline mask-dtype detect)
//         ∥  cast_scope (4096 blocks)
//         ∥  transpose_w (64 blocks)
// lm blocks first: longest-running, start immediately; cast/transpose fill in.
// Shared LDS arena (37424 B) aliased per branch.
// ---------------------------------------------------------------------------
#define LM_BLOCKS   512
#define CAST_BLOCKS 4096        // (S_*64)/256
#define TW_BLOCKS   64
#define SM_CAND     0           // float[32][260]  = 33280 B
#define SM_MLIST    33280       // int[1024]       =  4096 B
#define SM_TMASK    37376       // uchar[32]
#define SM_MCNT     37408
#define SM_FA       37412
#define SM_FB       37416
#define SM_SIZE     37424

__global__ __launch_bounds__(256) void fused_prep_lm(
    const float* __restrict__ scope, const float* __restrict__ W,
    float* __restrict__ Wt, unsigned short* __restrict__ scb,
    const int* __restrict__ lm_idx, const int* __restrict__ batch_pts,
    const void* __restrict__ tree_mask, float* __restrict__ out) {
  __shared__ __align__(16) char smem[SM_SIZE];
  const int bid = blockIdx.x;
  const int t   = threadIdx.x;

  if (bid < LM_BLOCKS) {
    // ------------------------- lm_preds -------------------------
    float (*cand)[260]   = reinterpret_cast<float(*)[260]>(smem + SM_CAND);
    int*  mlist          = reinterpret_cast<int*>(smem + SM_MLIST);
    unsigned char* tmask = reinterpret_cast<unsigned char*>(smem + SM_TMASK);
    int*  mcnt           = reinterpret_cast<int*>(smem + SM_MCNT);
    int*  fA             = reinterpret_cast<int*>(smem + SM_FA);
    int*  fB             = reinterpret_cast<int*>(smem + SM_FB);
    const int b  = bid >> 4;
    const int n0 = (bid & 15) * 32;

    if (t == 0) { *mcnt = 0; *fA = 0; *fB = 0; }
    __syncthreads();

    // inline mask-dtype detect: scan first 16384 bytes of tree_mask.
    // flag = 1 (bool), 2 (f32), 0 (i32): bytes @ r==1 nonzero -> bool;
    // else bytes @ r==3 nonzero -> f32; else i32.
    {
      const uint4* tw = reinterpret_cast<const uint4*>(tree_mask);
      unsigned int aa = 0, bb = 0;
#pragma unroll
      for (int i = 0; i < 4; i++) {
        const uint4 w = tw[t + i * 256];
        aa |= (w.x >> 8) & 0xffu;  bb |= w.x >> 24;
        aa |= (w.y >> 8) & 0xffu;  bb |= w.y >> 24;
        aa |= (w.z >> 8) & 0xffu;  bb |= w.z >> 24;
        aa |= (w.w >> 8) & 0xffu;  bb |= w.w >> 24;
      }
      if (aa) atomicOr(fA, 1);
      if (bb) atomicOr(fB, 1);
    }

    // stage 32 candidate rows
    {
      const int lane = t & 63;
      const int r0   = t >> 6;
#pragma unroll
      for (int rr = 0; rr < 8; rr++) {
        const int row = rr * 4 + r0;
        const float4 v = *reinterpret_cast<const float4*>(
            scope + (size_t)(b * N_ + n0 + row) * TD_ + lane * 4);
        float* dst = &cand[row][lane * 4];
        dst[0] = v.x; dst[1] = v.y; dst[2] = v.z; dst[3] = v.w;
      }
    }
    __syncthreads();

    const int flag = *fA ? 1 : (*fB ? 2 : 0);
    if (t < 32) {
      const int n = b * N_ + n0 + t;
      int v;
      if (flag == 1)      v = ((const unsigned char*)tree_mask)[n] != 0;
      else if (flag == 2) v = ((const float*)tree_mask)[n] != 0.0f;
      else                v = ((const int*)tree_mask)[n] != 0;
      tmask[t] = (unsigned char)v;
    }

#pragma unroll
    for (int c = 0; c < M_ / 256; c++) {
      const int m = c * 256 + t;
      if (batch_pts[m] == b) {
        const int p = atomicAdd(mcnt, 1);
        mlist[p] = m;
      }
    }
    __syncthreads();
    const int cnt = *mcnt;

    const int nl = t >> 3;
    const int kg = t & 7;
    for (int k = 0; k < cnt; k++) {
      const int m = mlist[k];
      const float4* q =
          reinterpret_cast<const float4*>(scope + (size_t)lm_idx[m] * D_);
      float acc = 0.f;
#pragma unroll
      for (int i = 0; i < 8; i++) {
        const int f4 = kg * 8 + i;
        const float4 qv = q[f4];
        const float* cp = &cand[nl][f4 * 4];
        acc += qv.x * cp[0] + qv.y * cp[1] + qv.z * cp[2] + qv.w * cp[3];
      }
      acc += __shfl_xor(acc, 1);
      acc += __shfl_xor(acc, 2);
      acc += __shfl_xor(acc, 4);
      if (kg == 0)
        out[(size_t)m * N_ + (n0 + nl)] = tmask[nl] ? acc : NEG_;
    }
  } else if (bid < LM_BLOCKS + CAST_BLOCKS) {
    // ------------------------- cast_scope -------------------------
    const int q   = (bid - LM_BLOCKS) * 256 + t;   // quad id, < 16384*64
    const int row = q >> 6;
    const int c4  = q & 63;
    const float4 v =
        *reinterpret_cast<const float4*>(scope + (size_t)row * TD_ + c4 * 4);
    ushort4 o;
    o.x = f2bf(v.x); o.y = f2bf(v.y); o.z = f2bf(v.z); o.w = f2bf(v.w);
    *reinterpret_cast<ushort4*>(&scb[(size_t)row * D_ + c4 * 4]) = o;
  } else {
    // ------------------------- transpose_w -------------------------
    float (*tile)[33] = reinterpret_cast<float(*)[33]>(smem);
    const int tb = bid - (LM_BLOCKS + CAST_BLOCKS);
    const int bi = tb >> 3;
    const int bj = tb & 7;
    const int tx = t & 31;
    const int ty = t >> 5;
#pragma unroll
    for (int r = 0; r < 4; r++)
      tile[ty + r * 8][tx] =
          W[(size_t)(bi * 32 + ty + r * 8) * D_ + bj * 32 + tx];
    __syncthreads();
#pragma unroll
    for (int r = 0; r < 4; r++)
      Wt[(size_t)(bj * 32 + ty + r * 8) * D_ + bi * 32 + tx] =
          tile[tx][ty + r * 8];
  }
}

// ---------------------------------------------------------------------------
// K2: Wg_bf16[j][d] = bf16( sum_f goal_type[j][f] * Wt[f][d] )
// fp32 math, bf16 store (feeds the per-edge dot). Unchanged — verified.
// ---------------------------------------------------------------------------
__global__ __launch_bounds__(256) void wg_gemm(
    const float* __restrict__ goal, const float* __restrict__ Wt,
    unsigned short* __restrict__ Wgb) {
  __shared__ float g[8][256];
  const int j0 = blockIdx.x * 8;
  const int d  = threadIdx.x;
  {
    const int lane = threadIdx.x & 63;
    const int r0   = threadIdx.x >> 6;
#pragma unroll
    for (int rr = 0; rr < 2; rr++) {
      const int row = rr * 4 + r0;
      const float4 v = *reinterpret_cast<const float4*>(
          goal + (size_t)(j0 + row) * TD_ + lane * 4);
      float* dst = &g[row][lane * 4];
      dst[0] = v.x; dst[1] = v.y; dst[2] = v.z; dst[3] = v.w;
    }
  }
  __syncthreads();
  float acc[8];
#pragma unroll
  for (int jj = 0; jj < 8; jj++) acc[jj] = 0.f;
#pragma unroll 4
  for (int f = 0; f < D_; f++) {
    const float w = Wt[(size_t)f * D_ + d];
#pragma unroll
    for (int jj = 0; jj < 8; jj++) acc[jj] = fmaf(g[jj][f], w, acc[jj]);
  }
#pragma unroll
  for (int jj = 0; jj < 8; jj++)
    Wgb[(size_t)(j0 + jj) * D_ + d] = f2bf(acc[jj]);
}

// ---------------------------------------------------------------------------
// K3: per-edge dot — lemma_preds[e] = Sc[src_e] . Wg[tgt_e] + bias.
// 8 lanes per edge, 32 bf16 elems/lane (4x b128 each side = 8 loads in
// flight per lane), 3-stage shfl_xor reduce. 32 edges/block, exact grid.
// ---------------------------------------------------------------------------
__global__ __launch_bounds__(256) void edge_dot(
    const unsigned short* __restrict__ scb,
    const unsigned short* __restrict__ wgb,
    const int* __restrict__ edges, const float* __restrict__ bias,
    float* __restrict__ out) {
  const int tid = threadIdx.x;
  const int grp = tid >> 3;                 // 32 edges per block
  const int l   = tid & 7;
  const int e   = blockIdx.x * 32 + grp;    // 15625*32 == E_: no guard
  const int s = edges[e];
  const int t = edges[E_ + e];
  const size_t sa = (size_t)s * D_;
  const size_t ta = (size_t)t * D_;
  short8 a[4], b[4];
#pragma unroll
  for (int i = 0; i < 4; i++) {
    a[i] = *reinterpret_cast<const short8*>(&scb[sa + i * 64 + l * 8]);
    b[i] = *reinterpret_cast<const short8*>(&wgb[ta + i * 64 + l * 8]);
  }
  float acc = 0.f;
#pragma unroll
  for (int i = 0; i < 4; i++)
#pragma unroll
    for (int j = 0; j < 8; j++)
      acc = fmaf(bf2f((unsigned short)a[i][j]),
                 bf2f((unsigned short)b[i][j]), acc);
  acc += __shfl_xor(acc, 1);
  acc += __shfl_xor(acc, 2);
  acc += __shfl_xor(acc, 4);
  if (l == 0) out[e] = acc + bias[0];
}

// ---------------------------------------------------------------------------
extern "C" void kernel_launch(void* const* d_in, const int* in_sizes, int n_in,
                              void* d_out, int out_size, void* d_ws,
                              size_t ws_size, hipStream_t stream) {
  const float* scope = (const float*)d_in[0];
  const float* goal  = (const float*)d_in[1];
  const float* W     = (const float*)d_in[2];
  const float* bias  = (const float*)d_in[3];
  const int*   edges = (const int*)d_in[4];
  const int*   lmidx = (const int*)d_in[5];
  const int*   bpts  = (const int*)d_in[6];
  const void*  tmask = d_in[7];

  float* out = (float*)d_out;
  char*  ws  = (char*)d_ws;
  float*          Wt   = (float*)(ws + WS_WT);
  unsigned short* Wgb  = (unsigned short*)(ws + WS_WGB);
  unsigned short* scb  = (unsigned short*)(ws + WS_SCB);

  fused_prep_lm<<<LM_BLOCKS + CAST_BLOCKS + TW_BLOCKS, 256, 0, stream>>>(
      scope, W, Wt, scb, lmidx, bpts, tmask, out + E_);
  wg_gemm<<<TT_ / 8, 256, 0, stream>>>(goal, Wt, Wgb);
  edge_dot<<<E_ / 32, 256, 0, stream>>>(scb, Wgb, edges, bias, out);
}

// Round 7
// 431.555 us; speedup vs baseline: 1.1210x; 1.0141x over previous
//
#include <hip/hip_runtime.h>

#define B_   32
#define N_   512
#define G_   64
#define T_   16
#define D_   256
#define E_   500000
#define M_   1024
#define S_   (B_ * N_)          // 16384 distinct source rows
#define TT_  2048               // B_*G_ distinct target rows
#define TD_  (T_ * D_)          // 4096 floats between scope_type rows
#define NEG_ (-10000000000.0f)

// ws layout (bytes)
#define WS_WGB   262144         // 1 MiB    (Wg bf16, 2048x256)
#define WS_SCB   2097152        // 8 MiB    (scope_type bf16, 16384x256)

typedef short  short8 __attribute__((ext_vector_type(8)));

__device__ __forceinline__ unsigned short f2bf(float x) {
  union { float f; unsigned int u; } v; v.f = x;
  const unsigned int r = (v.u + 0x7fffu + ((v.u >> 16) & 1u)) >> 16;
  return (unsigned short)r;
}

__device__ __forceinline__ float bf2f(unsigned short u) {
  union { unsigned int u; float f; } v;
  v.u = ((unsigned int)u) << 16;
  return v.f;
}

// ---------------------------------------------------------------------------
// K1: fused  lm_kernel (512 blocks, inline mask-dtype detect)
//         ∥  cast_scope (4096 blocks)
//         ∥  wg_gemm (256 blocks, W-direct: thread d streams its own W row,
//              64B lines L1-resident for 16 f-iters — no transpose needed)
// transpose_w deleted; wg_gemm launch deleted → 2-dispatch pipeline.
// Shared LDS arena (37424 B) aliased per branch.
// ---------------------------------------------------------------------------
#define LM_BLOCKS   512
#define CAST_BLOCKS 4096        // (S_*64)/256
#define WG_BLOCKS   256         // TT_/8
#define SM_CAND     0           // float[32][260]  = 33280 B
#define SM_MLIST    33280       // int[1024]       =  4096 B
#define SM_TMASK    37376       // uchar[32]
#define SM_MCNT     37408
#define SM_FA       37412
#define SM_FB       37416
#define SM_SIZE     37424

__global__ __launch_bounds__(256) void fused_prep_lm(
    const float* __restrict__ scope, const float* __restrict__ goal,
    const float* __restrict__ W, unsigned short* __restrict__ Wgb,
    unsigned short* __restrict__ scb, const int* __restrict__ lm_idx,
    const int* __restrict__ batch_pts, const void* __restrict__ tree_mask,
    float* __restrict__ out) {
  __shared__ __align__(16) char smem[SM_SIZE];
  const int bid = blockIdx.x;
  const int t   = threadIdx.x;

  if (bid < LM_BLOCKS) {
    // ------------------------- lm_preds -------------------------
    float (*cand)[260]   = reinterpret_cast<float(*)[260]>(smem + SM_CAND);
    int*  mlist          = reinterpret_cast<int*>(smem + SM_MLIST);
    unsigned char* tmask = reinterpret_cast<unsigned char*>(smem + SM_TMASK);
    int*  mcnt           = reinterpret_cast<int*>(smem + SM_MCNT);
    int*  fA             = reinterpret_cast<int*>(smem + SM_FA);
    int*  fB             = reinterpret_cast<int*>(smem + SM_FB);
    const int b  = bid >> 4;
    const int n0 = (bid & 15) * 32;

    if (t == 0) { *mcnt = 0; *fA = 0; *fB = 0; }
    __syncthreads();

    // inline mask-dtype detect: scan first 16384 bytes of tree_mask.
    // flag = 1 (bool), 2 (f32), 0 (i32): bytes @ r==1 nonzero -> bool;
    // else bytes @ r==3 nonzero -> f32; else i32.
    {
      const uint4* tw = reinterpret_cast<const uint4*>(tree_mask);
      unsigned int aa = 0, bb = 0;
#pragma unroll
      for (int i = 0; i < 4; i++) {
        const uint4 w = tw[t + i * 256];
        aa |= (w.x >> 8) & 0xffu;  bb |= w.x >> 24;
        aa |= (w.y >> 8) & 0xffu;  bb |= w.y >> 24;
        aa |= (w.z >> 8) & 0xffu;  bb |= w.z >> 24;
        aa |= (w.w >> 8) & 0xffu;  bb |= w.w >> 24;
      }
      if (aa) atomicOr(fA, 1);
      if (bb) atomicOr(fB, 1);
    }

    // stage 32 candidate rows
    {
      const int lane = t & 63;
      const int r0   = t >> 6;
#pragma unroll
      for (int rr = 0; rr < 8; rr++) {
        const int row = rr * 4 + r0;
        const float4 v = *reinterpret_cast<const float4*>(
            scope + (size_t)(b * N_ + n0 + row) * TD_ + lane * 4);
        float* dst = &cand[row][lane * 4];
        dst[0] = v.x; dst[1] = v.y; dst[2] = v.z; dst[3] = v.w;
      }
    }
    __syncthreads();

    const int flag = *fA ? 1 : (*fB ? 2 : 0);
    if (t < 32) {
      const int n = b * N_ + n0 + t;
      int v;
      if (flag == 1)      v = ((const unsigned char*)tree_mask)[n] != 0;
      else if (flag == 2) v = ((const float*)tree_mask)[n] != 0.0f;
      else                v = ((const int*)tree_mask)[n] != 0;
      tmask[t] = (unsigned char)v;
    }

#pragma unroll
    for (int c = 0; c < M_ / 256; c++) {
      const int m = c * 256 + t;
      if (batch_pts[m] == b) {
        const int p = atomicAdd(mcnt, 1);
        mlist[p] = m;
      }
    }
    __syncthreads();
    const int cnt = *mcnt;

    const int nl = t >> 3;
    const int kg = t & 7;
    for (int k = 0; k < cnt; k++) {
      const int m = mlist[k];
      const float4* q =
          reinterpret_cast<const float4*>(scope + (size_t)lm_idx[m] * D_);
      float acc = 0.f;
#pragma unroll
      for (int i = 0; i < 8; i++) {
        const int f4 = kg * 8 + i;
        const float4 qv = q[f4];
        const float* cp = &cand[nl][f4 * 4];
        acc += qv.x * cp[0] + qv.y * cp[1] + qv.z * cp[2] + qv.w * cp[3];
      }
      acc += __shfl_xor(acc, 1);
      acc += __shfl_xor(acc, 2);
      acc += __shfl_xor(acc, 4);
      if (kg == 0)
        out[(size_t)m * N_ + (n0 + nl)] = tmask[nl] ? acc : NEG_;
    }
  } else if (bid < LM_BLOCKS + CAST_BLOCKS) {
    // ------------------------- cast_scope -------------------------
    const int q   = (bid - LM_BLOCKS) * 256 + t;   // quad id, < 16384*64
    const int row = q >> 6;
    const int c4  = q & 63;
    const float4 v =
        *reinterpret_cast<const float4*>(scope + (size_t)row * TD_ + c4 * 4);
    ushort4 o;
    o.x = f2bf(v.x); o.y = f2bf(v.y); o.z = f2bf(v.z); o.w = f2bf(v.w);
    *reinterpret_cast<ushort4*>(&scb[(size_t)row * D_ + c4 * 4]) = o;
  } else {
    // ------------------------- wg_gemm (W-direct) -------------------------
    // Wgb[j][d] = bf16( sum_f goal_type[j][f] * W[d][f] ),  8 j-rows/block.
    float (*g)[256] = reinterpret_cast<float(*)[256]>(smem);
    const int j0 = (bid - (LM_BLOCKS + CAST_BLOCKS)) * 8;
    const int d  = t;
    {
      const int lane = t & 63;
      const int r0   = t >> 6;
#pragma unroll
      for (int rr = 0; rr < 2; rr++) {
        const int row = rr * 4 + r0;
        const float4 v = *reinterpret_cast<const float4*>(
            goal + (size_t)(j0 + row) * TD_ + lane * 4);
        float* dst = &g[row][lane * 4];
        dst[0] = v.x; dst[1] = v.y; dst[2] = v.z; dst[3] = v.w;
      }
    }
    __syncthreads();
    float acc[8];
#pragma unroll
    for (int jj = 0; jj < 8; jj++) acc[jj] = 0.f;
    const float* wrow = W + (size_t)d * D_;   // W[d][f], f contiguous
#pragma unroll 4
    for (int f = 0; f < D_; f++) {
      const float w = wrow[f];
#pragma unroll
      for (int jj = 0; jj < 8; jj++) acc[jj] = fmaf(g[jj][f], w, acc[jj]);
    }
#pragma unroll
    for (int jj = 0; jj < 8; jj++)
      Wgb[(size_t)(j0 + jj) * D_ + d] = f2bf(acc[jj]);
  }
}

// ---------------------------------------------------------------------------
// K3: per-edge dot — lemma_preds[e] = Sc[src_e] . Wg[tgt_e] + bias.
// 8 lanes per edge, 32 bf16 elems/lane (4x b128 each side = 8 loads in
// flight per lane), 2-way acc ILP, 3-stage shfl_xor reduce. 32 edges/block.
// ---------------------------------------------------------------------------
__global__ __launch_bounds__(256) void edge_dot(
    const unsigned short* __restrict__ scb,
    const unsigned short* __restrict__ wgb,
    const int* __restrict__ edges, const float* __restrict__ bias,
    float* __restrict__ out) {
  const int tid = threadIdx.x;
  const int grp = tid >> 3;                 // 32 edges per block
  const int l   = tid & 7;
  const int e   = blockIdx.x * 32 + grp;    // 15625*32 == E_: no guard
  const int s = edges[e];
  const int t = edges[E_ + e];
  const size_t sa = (size_t)s * D_;
  const size_t ta = (size_t)t * D_;
  short8 a[4], b[4];
#pragma unroll
  for (int i = 0; i < 4; i++) {
    a[i] = *reinterpret_cast<const short8*>(&scb[sa + i * 64 + l * 8]);
    b[i] = *reinterpret_cast<const short8*>(&wgb[ta + i * 64 + l * 8]);
  }
  float acc0 = 0.f, acc1 = 0.f;
#pragma unroll
  for (int i = 0; i < 2; i++)
#pragma unroll
    for (int j = 0; j < 8; j++) {
      acc0 = fmaf(bf2f((unsigned short)a[i][j]),
                  bf2f((unsigned short)b[i][j]), acc0);
      acc1 = fmaf(bf2f((unsigned short)a[i + 2][j]),
                  bf2f((unsigned short)b[i + 2][j]), acc1);
    }
  float acc = acc0 + acc1;
  acc += __shfl_xor(acc, 1);
  acc += __shfl_xor(acc, 2);
  acc += __shfl_xor(acc, 4);
  if (l == 0) out[e] = acc + bias[0];
}

// ---------------------------------------------------------------------------
extern "C" void kernel_launch(void* const* d_in, const int* in_sizes, int n_in,
                              void* d_out, int out_size, void* d_ws,
                              size_t ws_size, hipStream_t stream) {
  const float* scope = (const float*)d_in[0];
  const float* goal  = (const float*)d_in[1];
  const float* W     = (const float*)d_in[2];
  const float* bias  = (const float*)d_in[3];
  const int*   edges = (const int*)d_in[4];
  const int*   lmidx = (const int*)d_in[5];
  const int*   bpts  = (const int*)d_in[6];
  const void*  tmask = d_in[7];

  float* out = (float*)d_out;
  char*  ws  = (char*)d_ws;
  unsigned short* Wgb  = (unsigned short*)(ws + WS_WGB);
  unsigned short* scb  = (unsigned short*)(ws + WS_SCB);

  fused_prep_lm<<<LM_BLOCKS + CAST_BLOCKS + WG_BLOCKS, 256, 0, stream>>>(
      scope, goal, W, Wgb, scb, lmidx, bpts, tmask, out + E_);
  edge_dot<<<E_ / 32, 256, 0, stream>>>(scb, Wgb, edges, bias, out);
}